// Round 14
// baseline (165.437 us; speedup 1.0000x reference)
//
#include <hip/hip_runtime.h>

typedef __bf16 bf16;
typedef __bf16 bf16x8 __attribute__((ext_vector_type(8)));
typedef __bf16 bf16x4 __attribute__((ext_vector_type(4)));
typedef float  f32x4  __attribute__((ext_vector_type(4)));

#define B_ 2
#define L_ 8
#define N_ 256
#define C_ 1024
#define H_ 16
#define D_ 64
#define T_ 2048
#define M_ 4096
#define COND_ 64

// 0.125 * log2(e)
#define QSCALE 0.18033688011111372f

__device__ __forceinline__ void gload_lds16(const void* g, void* lds) {
  __builtin_amdgcn_global_load_lds((const __attribute__((address_space(1))) void*)g,
                                   (__attribute__((address_space(3))) void*)lds, 16, 0, 0);
}

// ---------------- ada: ss[b][j] = cond[b] @ W_ada[:,j] + b_ada[j] ----------------
__global__ __launch_bounds__(256) void k_ada(const float* __restrict__ cond,
                                             const float* __restrict__ W,
                                             const float* __restrict__ ba,
                                             float* __restrict__ ss) {
  int j = blockIdx.x * 256 + threadIdx.x;   // 0..4095
  int b = j >> 11;
  int n = j & 2047;
  float s = ba[n];
  #pragma unroll
  for (int i = 0; i < COND_; ++i) s += cond[b * COND_ + i] * W[i * 2048 + n];
  ss[j] = s;
}

// ---------------- weight transpose + cast: Wt[z*1024 + n][k] = W_z[k][n] ----------------
__global__ __launch_bounds__(256) void k_wt(const float* __restrict__ Wq,
                                            const float* __restrict__ Wk,
                                            const float* __restrict__ Wv,
                                            const float* __restrict__ Wo,
                                            bf16* __restrict__ Wt) {
  __shared__ float lds[64][65];
  int z = blockIdx.z;
  const float* W = (z == 0) ? Wq : (z == 1) ? Wk : (z == 2) ? Wv : Wo;
  int k0 = blockIdx.y * 64, n0 = blockIdx.x * 64;
  int tid = threadIdx.x;
  int r = tid >> 4, c4 = (tid & 15) * 4;
  #pragma unroll
  for (int p = 0; p < 4; ++p) {
    float4 v = *(const float4*)&W[(size_t)(k0 + p * 16 + r) * 1024 + n0 + c4];
    lds[p * 16 + r][c4] = v.x; lds[p * 16 + r][c4 + 1] = v.y;
    lds[p * 16 + r][c4 + 2] = v.z; lds[p * 16 + r][c4 + 3] = v.w;
  }
  __syncthreads();
  #pragma unroll
  for (int p = 0; p < 4; ++p) {
    int j = p * 16 + r;   // n-local
    int i0 = c4;          // k-local
    bf16x4 o;
    o[0] = (bf16)lds[i0][j]; o[1] = (bf16)lds[i0 + 1][j];
    o[2] = (bf16)lds[i0 + 2][j]; o[3] = (bf16)lds[i0 + 3][j];
    *(bf16x4*)&Wt[(size_t)(z * 1024 + n0 + j) * 1024 + k0 + i0] = o;
  }
}

// ---------------- LayerNorm + AdaLN modulation -> bf16 ----------------
__global__ __launch_bounds__(256) void k_ln(const float* __restrict__ x,
                                            const float* __restrict__ ss,
                                            bf16* __restrict__ xo) {
  int row = blockIdx.x;          // b*T + t
  int b = row >> 11;
  int tid = threadIdx.x;
  float4 v = *(const float4*)&x[(size_t)row * 1024 + tid * 4];
  float s = v.x + v.y + v.z + v.w;
  float s2 = v.x * v.x + v.y * v.y + v.z * v.z + v.w * v.w;
  #pragma unroll
  for (int o = 32; o > 0; o >>= 1) { s += __shfl_down(s, o); s2 += __shfl_down(s2, o); }
  __shared__ float rs[4], rs2[4];
  int w = tid >> 6, l = tid & 63;
  if (l == 0) { rs[w] = s; rs2[w] = s2; }
  __syncthreads();
  s = rs[0] + rs[1] + rs[2] + rs[3];
  s2 = rs2[0] + rs2[1] + rs2[2] + rs2[3];
  float mu = s * (1.f / 1024.f);
  float var = s2 * (1.f / 1024.f) - mu * mu;
  float rinv = rsqrtf(var + 1e-5f);
  int c = tid * 4;
  float4 sh = *(const float4*)&ss[b * 2048 + c];
  float4 sc = *(const float4*)&ss[b * 2048 + 1024 + c];
  bf16x4 o;
  o[0] = (bf16)((v.x - mu) * rinv * (1.f + sc.x) + sh.x);
  o[1] = (bf16)((v.y - mu) * rinv * (1.f + sc.y) + sh.y);
  o[2] = (bf16)((v.z - mu) * rinv * (1.f + sc.z) + sh.z);
  o[3] = (bf16)((v.w - mu) * rinv * (1.f + sc.w) + sh.w);
  *(bf16x4*)&xo[(size_t)row * 1024 + c] = o;
}

// ---------------- QKV GEMM: 64x128 tile, depth-2 prefetch (3 LDS bufs), T2 swizzle ----------------
// r12-proven version, verbatim. A: M x 1024 bf16; Bt: 3072 x 1024 bf16. Grid (24, 64).
// bx<8: q, 8..15: k, 16..23: v.
__global__ __launch_bounds__(256) void k_gemm_qkv(const bf16* __restrict__ A,
                                                  const bf16* __restrict__ Bt,
                                                  const float* __restrict__ bq,
                                                  const float* __restrict__ bk,
                                                  const float* __restrict__ bv,
                                                  const int* __restrict__ seq_idx,
                                                  const int* __restrict__ frame_idx,
                                                  bf16* __restrict__ qkv,
                                                  bf16* __restrict__ vt) {
  __shared__ __attribute__((aligned(16))) bf16 As[3][64 * 32];
  __shared__ __attribute__((aligned(16))) bf16 Bs[3][128 * 32];
  const int K = 1024;
  int n0 = blockIdx.x * 128, m0 = blockIdx.y * 64;
  int tid = threadIdx.x;
  int w = tid >> 6, l = tid & 63, cc = l & 15, g = l >> 4;
  int wm = w >> 1, wn = w & 1;
  f32x4 acc[2][4] = {};
  // pre-swizzled source chunk: (tid&3) ^ ((tid>>3)&3); dest row = tid>>2 (+64 for B's 2nd gload)
  int pxg = ((tid & 3) ^ ((tid >> 3) & 3)) * 8;
  const bf16* Ag = A + (size_t)(m0 + (tid >> 2)) * K + pxg;
  const bf16* Bg = Bt + (size_t)(n0 + (tid >> 2)) * K + pxg;
  int soff = w * 512;
  #define GSTAGE(buf, kt_)                                                      \
    do {                                                                        \
      gload_lds16(Ag + (kt_) * 32, &As[buf][soff]);                             \
      gload_lds16(Bg + (kt_) * 32, &Bs[buf][soff]);                             \
      gload_lds16(Bg + (kt_) * 32 + (size_t)64 * K, &Bs[buf][soff + 2048]);     \
    } while (0)
  GSTAGE(0, 0);
  GSTAGE(1, 1);
  int c0 = 0, c1 = 1, c2 = 2;
  int swz = (g ^ ((cc >> 1) & 3)) * 8;     // read-side swizzle (row bits from cc only)
  for (int kt = 0; kt < 32; ++kt) {
    if (kt + 2 < 32) {
      GSTAGE(c2, kt + 2);
      asm volatile("s_waitcnt vmcnt(6)" ::: "memory");
    } else if (kt + 1 < 32) {
      asm volatile("s_waitcnt vmcnt(3)" ::: "memory");
    } else {
      asm volatile("s_waitcnt vmcnt(0)" ::: "memory");
    }
    __builtin_amdgcn_s_barrier();
    asm volatile("" ::: "memory");
    bf16x8 a[2], bb[4];
    #pragma unroll
    for (int mi = 0; mi < 2; ++mi) a[mi] = *(const bf16x8*)&As[c0][(wm * 32 + mi * 16 + cc) * 32 + swz];
    #pragma unroll
    for (int ni = 0; ni < 4; ++ni) bb[ni] = *(const bf16x8*)&Bs[c0][(wn * 64 + ni * 16 + cc) * 32 + swz];
    #pragma unroll
    for (int mi = 0; mi < 2; ++mi)
      #pragma unroll
      for (int ni = 0; ni < 4; ++ni)
        acc[mi][ni] = __builtin_amdgcn_mfma_f32_16x16x32_bf16(a[mi], bb[ni], acc[mi][ni], 0, 0, 0);
    __builtin_amdgcn_s_barrier();
    asm volatile("" ::: "memory");
    int tmp = c0; c0 = c1; c1 = c2; c2 = tmp;
  }
  #undef GSTAGE
  int region = blockIdx.x >> 3;            // 0=q, 1=k, 2=v
  const float* bp = (region == 0) ? bq : (region == 1) ? bk : bv;
  int b = m0 >> 11;
  if (region < 2) {
    // ---- fused RoPE: pairs (ni0,ni1) with pos_s, (ni2,ni3) with pos_f ----
    float* Ps = (float*)&As[0][0];         // dead after the K-loop
    if (tid < 64) Ps[tid] = (float)seq_idx[b * 256 + (m0 & 255) + tid];
    __syncthreads();
    float invf = exp2f(-0.8304820237218405f * (float)cc);   // 10000^(-cc/16)
    float posf = (float)frame_idx[(m0 & 2047) >> 8];        // block-constant frame
    float snf, csf;
    sincosf(posf * invf, &snf, &csf);
    float scl = (region == 0) ? QSCALE : 1.0f;
    csf *= scl; snf *= scl;
    int colbase = n0 + wn * 64 + cc;
    float b0 = bp[colbase & 1023];
    float b1 = bp[(colbase + 16) & 1023];
    float b2 = bp[(colbase + 32) & 1023];
    float b3 = bp[(colbase + 48) & 1023];
    #pragma unroll
    for (int mi = 0; mi < 2; ++mi) {
      #pragma unroll
      for (int r = 0; r < 4; ++r) {
        int lr = wm * 32 + mi * 16 + g * 4 + r;
        float sns, css;
        sincosf(Ps[lr] * invf, &sns, &css);
        css *= scl; sns *= scl;
        float x0 = acc[mi][0][r] + b0;
        float x1 = acc[mi][1][r] + b1;
        float x2 = acc[mi][2][r] + b2;
        float x3 = acc[mi][3][r] + b3;
        bf16* op = qkv + (size_t)(m0 + lr) * 3072 + colbase;
        op[0]  = (bf16)(x0 * css - x1 * sns);
        op[16] = (bf16)(x0 * sns + x1 * css);
        op[32] = (bf16)(x2 * csf - x3 * snf);
        op[48] = (bf16)(x2 * snf + x3 * csf);
      }
    }
  } else {
    // ---- V: write directly transposed to vt[b][h][d][t] ----
    int h = (blockIdx.x - 16) * 2 + wn;
    int tbase = (m0 & 2047) + wm * 32;
    #pragma unroll
    for (int ni = 0; ni < 4; ++ni) {
      int d = ni * 16 + cc;
      float bias = bp[h * 64 + d];
      #pragma unroll
      for (int mi = 0; mi < 2; ++mi) {
        bf16x4 pk;
        #pragma unroll
        for (int r = 0; r < 4; ++r) pk[r] = (bf16)(acc[mi][ni][r] + bias);
        int t = tbase + mi * 16 + g * 4;
        *(bf16x4*)&vt[((size_t)(b * 16 + h) * 64 + d) * 2048 + t] = pk;
      }
    }
  }
}

// ---------------- Output GEMM: 64x128 tile, depth-2 prefetch, T2 swizzle, fp32 out ----------------
// A: 4096 x 1024 bf16 (att); Bt: 1024 x 1024 bf16 (Wo^T). Grid (8, 64).
__global__ __launch_bounds__(256) void k_gemm_o(const bf16* __restrict__ A,
                                                const bf16* __restrict__ Bt,
                                                const float* __restrict__ bo,
                                                float* __restrict__ out) {
  __shared__ __attribute__((aligned(16))) bf16 As[3][64 * 32];
  __shared__ __attribute__((aligned(16))) bf16 Bs[3][128 * 32];
  const int K = 1024;
  int n0 = blockIdx.x * 128, m0 = blockIdx.y * 64;
  int tid = threadIdx.x;
  int w = tid >> 6, l = tid & 63, cc = l & 15, g = l >> 4;
  int wm = w >> 1, wn = w & 1;
  f32x4 acc[2][4] = {};
  int pxg = ((tid & 3) ^ ((tid >> 3) & 3)) * 8;
  const bf16* Ag = A + (size_t)(m0 + (tid >> 2)) * K + pxg;
  const bf16* Bg = Bt + (size_t)(n0 + (tid >> 2)) * K + pxg;
  int soff = w * 512;
  #define GSTAGE(buf, kt_)                                                      \
    do {                                                                        \
      gload_lds16(Ag + (kt_) * 32, &As[buf][soff]);                             \
      gload_lds16(Bg + (kt_) * 32, &Bs[buf][soff]);                             \
      gload_lds16(Bg + (kt_) * 32 + (size_t)64 * K, &Bs[buf][soff + 2048]);     \
    } while (0)
  GSTAGE(0, 0);
  GSTAGE(1, 1);
  int c0 = 0, c1 = 1, c2 = 2;
  int swz = (g ^ ((cc >> 1) & 3)) * 8;
  for (int kt = 0; kt < 32; ++kt) {
    if (kt + 2 < 32) {
      GSTAGE(c2, kt + 2);
      asm volatile("s_waitcnt vmcnt(6)" ::: "memory");
    } else if (kt + 1 < 32) {
      asm volatile("s_waitcnt vmcnt(3)" ::: "memory");
    } else {
      asm volatile("s_waitcnt vmcnt(0)" ::: "memory");
    }
    __builtin_amdgcn_s_barrier();
    asm volatile("" ::: "memory");
    bf16x8 a[2], bb[4];
    #pragma unroll
    for (int mi = 0; mi < 2; ++mi) a[mi] = *(const bf16x8*)&As[c0][(wm * 32 + mi * 16 + cc) * 32 + swz];
    #pragma unroll
    for (int ni = 0; ni < 4; ++ni) bb[ni] = *(const bf16x8*)&Bs[c0][(wn * 64 + ni * 16 + cc) * 32 + swz];
    #pragma unroll
    for (int mi = 0; mi < 2; ++mi)
      #pragma unroll
      for (int ni = 0; ni < 4; ++ni)
        acc[mi][ni] = __builtin_amdgcn_mfma_f32_16x16x32_bf16(a[mi], bb[ni], acc[mi][ni], 0, 0, 0);
    __builtin_amdgcn_s_barrier();
    asm volatile("" ::: "memory");
    int tmp = c0; c0 = c1; c1 = c2; c2 = tmp;
  }
  #undef GSTAGE
  #pragma unroll
  for (int ni = 0; ni < 4; ++ni) {
    int col = n0 + wn * 64 + ni * 16 + cc;
    float bias = bo[col];
    #pragma unroll
    for (int mi = 0; mi < 2; ++mi)
      #pragma unroll
      for (int r = 0; r < 4; ++r) {
        int row = m0 + wm * 32 + mi * 16 + g * 4 + r;
        out[(size_t)row * 1024 + col] = acc[mi][ni][r] + bias;
      }
  }
}

// ---------------- frame-causal flash attention, swapped-QK^T (lane-local P) ----------------
// r12-proven compute, plus: (1) XCD-grouped block remap — the 4 q-tiles sharing one
// (f,h,b) K/V stream get wid = tile*256 + gi, so wid%8 (XCD) is equal for siblings and
// their staging loads hit the same XCD's L2; heavy frames still dispatched first.
// (2) T5 s_setprio(1) around QK^T and PV MFMA clusters. 4 blocks/CU (grid == capacity).
__global__ __launch_bounds__(256) void k_attn(const bf16* __restrict__ qkv,
                                              const bf16* __restrict__ vt,
                                              const int* __restrict__ mask,
                                              bf16* __restrict__ out) {
  __shared__ __attribute__((aligned(16))) bf16 Ks[2][64 * 64];   // [k][d-slot], slot = chunk ^ pi(k)
  __shared__ __attribute__((aligned(16))) bf16 Vs[2][64 * 64];   // [d][kv-slot], slot = chunk ^ (d&7)
  __shared__ int Ms[2048];
  int wid = blockIdx.x;
  int tile = wid >> 8;           // 0..3 (plane-major so siblings share wid%8 -> same XCD)
  int gi = wid & 255;            // group = (7-f)*32 + h*2 + b, heavy frames first
  int f = 7 - (gi >> 5);
  int rem2 = gi & 31;
  int h = rem2 >> 1;
  int b = rem2 & 1;
  int t0 = f * 256 + tile * 64;
  int nchunk = (f + 1) * 4;
  int tid = threadIdx.x;
  int w = tid >> 6, l = tid & 63, cc = l & 15, g = l >> 4;

  // staging: dest elem = w*1024 + l*8 (+j*512) -> row = w*16 + j*8 + (l>>3), slot = l&7
  int rbase = w * 16 + (l >> 3);
  int pxk = (l & 7) ^ ((l >> 3) & 3);  // K source chunk (j adds ^4): slot ^ pi(row)
  int pxv = (l & 7) ^ (l >> 3);        // V source chunk (original)
  int ldst = w * 1024 + l * 8;

  int trow = t0 + w * 16 + cc;
  const bf16* qp = qkv + (size_t)((size_t)b * T_ + trow) * 3072 + h * 64;
  bf16x8 aq0 = *(const bf16x8*)(qp + g * 8);
  bf16x8 aq1 = *(const bf16x8*)(qp + 32 + g * 8);
  f32x4 o[4] = {};
  f32x4 o1 = {0.f, 0.f, 0.f, 0.f};
  float m_p = -1e30f;                  // running max for q = cc (lane-local P rows)
  const int* mp = mask + b * T_;

  bf16x8 onesv;
  #pragma unroll
  for (int u = 0; u < 8; ++u) onesv[u] = (bf16)1.0f;

  // stage mask row once (8KB)
  #pragma unroll
  for (int j = 0; j < 2; ++j)
    gload_lds16(mp + w * 512 + j * 256 + l * 4, &Ms[w * 512 + j * 256 + l * 4]);

  #define STAGE(buf, s0_)                                                              \
    do {                                                                               \
      _Pragma("unroll")                                                                \
      for (int j = 0; j < 2; ++j) {                                                    \
        int r_ = rbase + j * 8;                                                        \
        gload_lds16(qkv + (size_t)((size_t)b * T_ + (s0_) + r_) * 3072 + 1024 + h * 64 + ((pxk ^ (j << 2)) << 3), \
                    &Ks[buf][ldst + j * 512]);                                         \
        gload_lds16(vt + (size_t)((size_t)(b * H_ + h) * 64 + r_) * T_ + (s0_) + (pxv << 3), \
                    &Vs[buf][ldst + j * 512]);                                         \
      }                                                                                \
    } while (0)

  STAGE(0, 0);
  // V read swizzle (rows = d, original): slot = chunk ^ (d&7), d&7 = cc&7
  int sw1 = (g ^ (cc & 7)) * 8;
  int sw2 = ((g + 4) ^ (cc & 7)) * 8;
  // K read swizzle (permuted rows rk): slot = chunk ^ pi(rk), pi(rk) = (cc&3)|(((cc>>2)&1)<<2)
  int pik = (cc & 3) | (((cc >> 2) & 1) << 2);
  int swk1 = (g ^ pik) * 8;
  int swk2 = ((g + 4) ^ pik) * 8;
  int rkbase = ((cc >> 2) << 3) | (cc & 3);   // sigma row base

  for (int scn = 0; scn < nchunk; ++scn) {
    int s0 = scn * 64;
    int cur = scn & 1;
    if (scn + 1 < nchunk) {
      STAGE(cur ^ 1, s0 + 64);
      asm volatile("s_waitcnt vmcnt(4)" ::: "memory");
    } else {
      asm volatile("s_waitcnt vmcnt(0)" ::: "memory");
    }
    __builtin_amdgcn_s_barrier();
    asm volatile("" ::: "memory");

    // swapped QK^T: sac[ni][r] = S[q=cc][kv = s0 + 8g + r + 4*(ni&1) + 32*(ni>>1)]
    f32x4 sac[4];
    __builtin_amdgcn_s_setprio(1);
    #pragma unroll
    for (int ni = 0; ni < 4; ++ni) {
      int rk = rkbase + ((ni & 1) << 2) + ((ni >> 1) << 5);
      bf16x8 k0 = *(const bf16x8*)&Ks[cur][rk * 64 + swk1];
      bf16x8 k1 = *(const bf16x8*)&Ks[cur][rk * 64 + swk2];
      f32x4 z = {0.f, 0.f, 0.f, 0.f};
      sac[ni] = __builtin_amdgcn_mfma_f32_16x16x32_bf16(k0, aq0, z, 0, 0, 0);
      sac[ni] = __builtin_amdgcn_mfma_f32_16x16x32_bf16(k1, aq1, sac[ni], 0, 0, 0);
    }
    __builtin_amdgcn_s_setprio(0);
    // mask bias: kv base = s0 + 8g + 4*(ni&1) + 32*(ni>>1), broadcast int4 reads
    #pragma unroll
    for (int ni = 0; ni < 4; ++ni) {
      const int4 mi = *(const int4*)&Ms[s0 + ((ni >> 1) << 5) + (g << 3) + ((ni & 1) << 2)];
      sac[ni][0] += mi.x ? 0.f : -1e30f;
      sac[ni][1] += mi.y ? 0.f : -1e30f;
      sac[ni][2] += mi.z ? 0.f : -1e30f;
      sac[ni][3] += mi.w ? 0.f : -1e30f;
    }

    // defer-max: lane-local 16-value max (all share q = cc)
    float pmax = sac[0][0];
    #pragma unroll
    for (int ni = 0; ni < 4; ++ni)
      #pragma unroll
      for (int r = 0; r < 4; ++r) pmax = fmaxf(pmax, sac[ni][r]);
    if (__any(pmax - m_p > 8.0f)) {
      float mx = pmax;
      mx = fmaxf(mx, __shfl_xor(mx, 16));
      mx = fmaxf(mx, __shfl_xor(mx, 32));
      float mn = fmaxf(m_p, mx);
      float alpha_p = exp2f(m_p - mn);
      m_p = mn;
      #pragma unroll
      for (int r = 0; r < 4; ++r) {
        float ao = __shfl(alpha_p, 4 * g + r);   // alpha for output row q = 4g+r
        #pragma unroll
        for (int ni = 0; ni < 4; ++ni) o[ni][r] *= ao;
        o1[r] *= ao;
      }
    }
    // P = exp2(S - m), pack into PV A-fragments (kv natural order: ap0 elem j = P[cc][8g+j])
    #pragma unroll
    for (int ni = 0; ni < 4; ++ni)
      #pragma unroll
      for (int r = 0; r < 4; ++r)
        sac[ni][r] = exp2f(sac[ni][r] - m_p);
    bf16x8 ap0, ap1;
    #pragma unroll
    for (int j = 0; j < 4; ++j) {
      ap0[j] = (bf16)sac[0][j]; ap0[4 + j] = (bf16)sac[1][j];
      ap1[j] = (bf16)sac[2][j]; ap1[4 + j] = (bf16)sac[3][j];
    }

    // PV + denominator via ones-MFMA (output rows q = 4g+r, cols d = ni*16+cc)
    __builtin_amdgcn_s_setprio(1);
    #pragma unroll
    for (int ni = 0; ni < 4; ++ni) {
      int d = ni * 16 + cc;
      bf16x8 v0 = *(const bf16x8*)&Vs[cur][d * 64 + sw1];
      bf16x8 v1 = *(const bf16x8*)&Vs[cur][d * 64 + sw2];
      o[ni] = __builtin_amdgcn_mfma_f32_16x16x32_bf16(ap0, v0, o[ni], 0, 0, 0);
      o[ni] = __builtin_amdgcn_mfma_f32_16x16x32_bf16(ap1, v1, o[ni], 0, 0, 0);
    }
    o1 = __builtin_amdgcn_mfma_f32_16x16x32_bf16(ap0, onesv, o1, 0, 0, 0);
    o1 = __builtin_amdgcn_mfma_f32_16x16x32_bf16(ap1, onesv, o1, 0, 0, 0);
    __builtin_amdgcn_s_setprio(0);

    __builtin_amdgcn_s_barrier();
    asm volatile("" ::: "memory");
  }
  float rl[4];
  #pragma unroll
  for (int r = 0; r < 4; ++r) rl[r] = 1.0f / o1[r];
  #pragma unroll
  for (int ni = 0; ni < 4; ++ni)
    #pragma unroll
    for (int r = 0; r < 4; ++r) {
      int t = t0 + w * 16 + g * 4 + r;
      out[(size_t)((size_t)b * T_ + t) * 1024 + h * 64 + ni * 16 + cc] = (bf16)(o[ni][r] * rl[r]);
    }
  #undef STAGE
}

extern "C" void kernel_launch(void* const* d_in, const int* in_sizes, int n_in,
                              void* d_out, int out_size, void* d_ws, size_t ws_size,
                              hipStream_t stream) {
  const float* s_frames = (const float*)d_in[0];
  const int* frame_idx  = (const int*)d_in[1];
  const int* seq_idx    = (const int*)d_in[2];
  const int* mask       = (const int*)d_in[3];
  const float* cond     = (const float*)d_in[4];
  const float* W_ada    = (const float*)d_in[5];
  const float* b_ada    = (const float*)d_in[6];
  const float* Wq       = (const float*)d_in[7];
  const float* bq       = (const float*)d_in[8];
  const float* Wk       = (const float*)d_in[9];
  const float* bk       = (const float*)d_in[10];
  const float* Wv       = (const float*)d_in[11];
  const float* bv       = (const float*)d_in[12];
  const float* Wo       = (const float*)d_in[13];
  const float* bo       = (const float*)d_in[14];
  float* out = (float*)d_out;

  char* ws = (char*)d_ws;
  float* ss = (float*)(ws);                                   // 16 KB
  bf16* xb  = (bf16*)(ws + 16384);                            // 8 MB
  bf16* Wt  = (bf16*)(ws + 16384 + 8388608);                  // 8 MB (4096x1024)
  bf16* qkv = (bf16*)(ws + 16384 + 2 * 8388608);              // 24 MB (4096x3072)
  bf16* vt  = (bf16*)(ws + 16384 + 2 * 8388608 + 25165824);   // 8 MB
  bf16* att = (bf16*)(ws + 16384 + 3 * 8388608 + 25165824);   // 8 MB

  k_ada<<<16, 256, 0, stream>>>(cond, W_ada, b_ada, ss);
  k_wt<<<dim3(16, 16, 4), 256, 0, stream>>>(Wq, Wk, Wv, Wo, Wt);
  k_ln<<<4096, 256, 0, stream>>>(s_frames, ss, xb);
  k_gemm_qkv<<<dim3(24, 64), 256, 0, stream>>>(xb, Wt, bq, bk, bv, seq_idx, frame_idx, qkv, vt);
  k_attn<<<1024, 256, 0, stream>>>(qkv, vt, mask, att);
  k_gemm_o<<<dim3(8, 64), 256, 0, stream>>>(att, Wt + (size_t)3072 * 1024, bo, out);
}

// Round 15
// 134.287 us; speedup vs baseline: 1.2320x; 1.2320x over previous
//
#include <hip/hip_runtime.h>

typedef __bf16 bf16;
typedef __bf16 bf16x8 __attribute__((ext_vector_type(8)));
typedef __bf16 bf16x4 __attribute__((ext_vector_type(4)));
typedef float  f32x4  __attribute__((ext_vector_type(4)));

#define B_ 2
#define L_ 8
#define N_ 256
#define C_ 1024
#define H_ 16
#define D_ 64
#define T_ 2048
#define M_ 4096
#define COND_ 64

// 0.125 * log2(e)
#define QSCALE 0.18033688011111372f

__device__ __forceinline__ void gload_lds16(const void* g, void* lds) {
  __builtin_amdgcn_global_load_lds((const __attribute__((address_space(1))) void*)g,
                                   (__attribute__((address_space(3))) void*)lds, 16, 0, 0);
}

// ---------------- ada: ss[b][j] = cond[b] @ W_ada[:,j] + b_ada[j] ----------------
__global__ __launch_bounds__(256) void k_ada(const float* __restrict__ cond,
                                             const float* __restrict__ W,
                                             const float* __restrict__ ba,
                                             float* __restrict__ ss) {
  int j = blockIdx.x * 256 + threadIdx.x;   // 0..4095
  int b = j >> 11;
  int n = j & 2047;
  float s = ba[n];
  #pragma unroll
  for (int i = 0; i < COND_; ++i) s += cond[b * COND_ + i] * W[i * 2048 + n];
  ss[j] = s;
}

// ---------------- weight transpose + cast: Wt[z*1024 + n][k] = W_z[k][n] ----------------
__global__ __launch_bounds__(256) void k_wt(const float* __restrict__ Wq,
                                            const float* __restrict__ Wk,
                                            const float* __restrict__ Wv,
                                            const float* __restrict__ Wo,
                                            bf16* __restrict__ Wt) {
  __shared__ float lds[64][65];
  int z = blockIdx.z;
  const float* W = (z == 0) ? Wq : (z == 1) ? Wk : (z == 2) ? Wv : Wo;
  int k0 = blockIdx.y * 64, n0 = blockIdx.x * 64;
  int tid = threadIdx.x;
  int r = tid >> 4, c4 = (tid & 15) * 4;
  #pragma unroll
  for (int p = 0; p < 4; ++p) {
    float4 v = *(const float4*)&W[(size_t)(k0 + p * 16 + r) * 1024 + n0 + c4];
    lds[p * 16 + r][c4] = v.x; lds[p * 16 + r][c4 + 1] = v.y;
    lds[p * 16 + r][c4 + 2] = v.z; lds[p * 16 + r][c4 + 3] = v.w;
  }
  __syncthreads();
  #pragma unroll
  for (int p = 0; p < 4; ++p) {
    int j = p * 16 + r;   // n-local
    int i0 = c4;          // k-local
    bf16x4 o;
    o[0] = (bf16)lds[i0][j]; o[1] = (bf16)lds[i0 + 1][j];
    o[2] = (bf16)lds[i0 + 2][j]; o[3] = (bf16)lds[i0 + 3][j];
    *(bf16x4*)&Wt[(size_t)(z * 1024 + n0 + j) * 1024 + k0 + i0] = o;
  }
}

// ---------------- LayerNorm + AdaLN modulation -> bf16 ----------------
__global__ __launch_bounds__(256) void k_ln(const float* __restrict__ x,
                                            const float* __restrict__ ss,
                                            bf16* __restrict__ xo) {
  int row = blockIdx.x;          // b*T + t
  int b = row >> 11;
  int tid = threadIdx.x;
  float4 v = *(const float4*)&x[(size_t)row * 1024 + tid * 4];
  float s = v.x + v.y + v.z + v.w;
  float s2 = v.x * v.x + v.y * v.y + v.z * v.z + v.w * v.w;
  #pragma unroll
  for (int o = 32; o > 0; o >>= 1) { s += __shfl_down(s, o); s2 += __shfl_down(s2, o); }
  __shared__ float rs[4], rs2[4];
  int w = tid >> 6, l = tid & 63;
  if (l == 0) { rs[w] = s; rs2[w] = s2; }
  __syncthreads();
  s = rs[0] + rs[1] + rs[2] + rs[3];
  s2 = rs2[0] + rs2[1] + rs2[2] + rs2[3];
  float mu = s * (1.f / 1024.f);
  float var = s2 * (1.f / 1024.f) - mu * mu;
  float rinv = rsqrtf(var + 1e-5f);
  int c = tid * 4;
  float4 sh = *(const float4*)&ss[b * 2048 + c];
  float4 sc = *(const float4*)&ss[b * 2048 + 1024 + c];
  bf16x4 o;
  o[0] = (bf16)((v.x - mu) * rinv * (1.f + sc.x) + sh.x);
  o[1] = (bf16)((v.y - mu) * rinv * (1.f + sc.y) + sh.y);
  o[2] = (bf16)((v.z - mu) * rinv * (1.f + sc.z) + sh.z);
  o[3] = (bf16)((v.w - mu) * rinv * (1.f + sc.w) + sh.w);
  *(bf16x4*)&xo[(size_t)row * 1024 + c] = o;
}

// ---------------- QKV GEMM: 64x128 tile, depth-2 prefetch (3 LDS bufs), T2 swizzle ----------------
// r12-proven version, verbatim. A: M x 1024 bf16; Bt: 3072 x 1024 bf16. Grid (24, 64).
// bx<8: q, 8..15: k, 16..23: v.
__global__ __launch_bounds__(256) void k_gemm_qkv(const bf16* __restrict__ A,
                                                  const bf16* __restrict__ Bt,
                                                  const float* __restrict__ bq,
                                                  const float* __restrict__ bk,
                                                  const float* __restrict__ bv,
                                                  const int* __restrict__ seq_idx,
                                                  const int* __restrict__ frame_idx,
                                                  bf16* __restrict__ qkv,
                                                  bf16* __restrict__ vt) {
  __shared__ __attribute__((aligned(16))) bf16 As[3][64 * 32];
  __shared__ __attribute__((aligned(16))) bf16 Bs[3][128 * 32];
  const int K = 1024;
  int n0 = blockIdx.x * 128, m0 = blockIdx.y * 64;
  int tid = threadIdx.x;
  int w = tid >> 6, l = tid & 63, cc = l & 15, g = l >> 4;
  int wm = w >> 1, wn = w & 1;
  f32x4 acc[2][4] = {};
  // pre-swizzled source chunk: (tid&3) ^ ((tid>>3)&3); dest row = tid>>2 (+64 for B's 2nd gload)
  int pxg = ((tid & 3) ^ ((tid >> 3) & 3)) * 8;
  const bf16* Ag = A + (size_t)(m0 + (tid >> 2)) * K + pxg;
  const bf16* Bg = Bt + (size_t)(n0 + (tid >> 2)) * K + pxg;
  int soff = w * 512;
  #define GSTAGE(buf, kt_)                                                      \
    do {                                                                        \
      gload_lds16(Ag + (kt_) * 32, &As[buf][soff]);                             \
      gload_lds16(Bg + (kt_) * 32, &Bs[buf][soff]);                             \
      gload_lds16(Bg + (kt_) * 32 + (size_t)64 * K, &Bs[buf][soff + 2048]);     \
    } while (0)
  GSTAGE(0, 0);
  GSTAGE(1, 1);
  int c0 = 0, c1 = 1, c2 = 2;
  int swz = (g ^ ((cc >> 1) & 3)) * 8;     // read-side swizzle (row bits from cc only)
  for (int kt = 0; kt < 32; ++kt) {
    if (kt + 2 < 32) {
      GSTAGE(c2, kt + 2);
      asm volatile("s_waitcnt vmcnt(6)" ::: "memory");
    } else if (kt + 1 < 32) {
      asm volatile("s_waitcnt vmcnt(3)" ::: "memory");
    } else {
      asm volatile("s_waitcnt vmcnt(0)" ::: "memory");
    }
    __builtin_amdgcn_s_barrier();
    asm volatile("" ::: "memory");
    bf16x8 a[2], bb[4];
    #pragma unroll
    for (int mi = 0; mi < 2; ++mi) a[mi] = *(const bf16x8*)&As[c0][(wm * 32 + mi * 16 + cc) * 32 + swz];
    #pragma unroll
    for (int ni = 0; ni < 4; ++ni) bb[ni] = *(const bf16x8*)&Bs[c0][(wn * 64 + ni * 16 + cc) * 32 + swz];
    #pragma unroll
    for (int mi = 0; mi < 2; ++mi)
      #pragma unroll
      for (int ni = 0; ni < 4; ++ni)
        acc[mi][ni] = __builtin_amdgcn_mfma_f32_16x16x32_bf16(a[mi], bb[ni], acc[mi][ni], 0, 0, 0);
    __builtin_amdgcn_s_barrier();
    asm volatile("" ::: "memory");
    int tmp = c0; c0 = c1; c1 = c2; c2 = tmp;
  }
  #undef GSTAGE
  int region = blockIdx.x >> 3;            // 0=q, 1=k, 2=v
  const float* bp = (region == 0) ? bq : (region == 1) ? bk : bv;
  int b = m0 >> 11;
  if (region < 2) {
    // ---- fused RoPE: pairs (ni0,ni1) with pos_s, (ni2,ni3) with pos_f ----
    float* Ps = (float*)&As[0][0];         // dead after the K-loop
    if (tid < 64) Ps[tid] = (float)seq_idx[b * 256 + (m0 & 255) + tid];
    __syncthreads();
    float invf = exp2f(-0.8304820237218405f * (float)cc);   // 10000^(-cc/16)
    float posf = (float)frame_idx[(m0 & 2047) >> 8];        // block-constant frame
    float snf, csf;
    sincosf(posf * invf, &snf, &csf);
    float scl = (region == 0) ? QSCALE : 1.0f;
    csf *= scl; snf *= scl;
    int colbase = n0 + wn * 64 + cc;
    float b0 = bp[colbase & 1023];
    float b1 = bp[(colbase + 16) & 1023];
    float b2 = bp[(colbase + 32) & 1023];
    float b3 = bp[(colbase + 48) & 1023];
    #pragma unroll
    for (int mi = 0; mi < 2; ++mi) {
      #pragma unroll
      for (int r = 0; r < 4; ++r) {
        int lr = wm * 32 + mi * 16 + g * 4 + r;
        float sns, css;
        sincosf(Ps[lr] * invf, &sns, &css);
        css *= scl; sns *= scl;
        float x0 = acc[mi][0][r] + b0;
        float x1 = acc[mi][1][r] + b1;
        float x2 = acc[mi][2][r] + b2;
        float x3 = acc[mi][3][r] + b3;
        bf16* op = qkv + (size_t)(m0 + lr) * 3072 + colbase;
        op[0]  = (bf16)(x0 * css - x1 * sns);
        op[16] = (bf16)(x0 * sns + x1 * css);
        op[32] = (bf16)(x2 * csf - x3 * snf);
        op[48] = (bf16)(x2 * snf + x3 * csf);
      }
    }
  } else {
    // ---- V: write directly transposed to vt[b][h][d][t] ----
    int h = (blockIdx.x - 16) * 2 + wn;
    int tbase = (m0 & 2047) + wm * 32;
    #pragma unroll
    for (int ni = 0; ni < 4; ++ni) {
      int d = ni * 16 + cc;
      float bias = bp[h * 64 + d];
      #pragma unroll
      for (int mi = 0; mi < 2; ++mi) {
        bf16x4 pk;
        #pragma unroll
        for (int r = 0; r < 4; ++r) pk[r] = (bf16)(acc[mi][ni][r] + bias);
        int t = tbase + mi * 16 + g * 4;
        *(bf16x4*)&vt[((size_t)(b * 16 + h) * 64 + d) * 2048 + t] = pk;
      }
    }
  }
}

// ---------------- Output GEMM: 64x128 tile, depth-2 prefetch, T2 swizzle, fp32 out ----------------
// A: 4096 x 1024 bf16 (att); Bt: 1024 x 1024 bf16 (Wo^T). Grid (8, 64).
__global__ __launch_bounds__(256) void k_gemm_o(const bf16* __restrict__ A,
                                                const bf16* __restrict__ Bt,
                                                const float* __restrict__ bo,
                                                float* __restrict__ out) {
  __shared__ __attribute__((aligned(16))) bf16 As[3][64 * 32];
  __shared__ __attribute__((aligned(16))) bf16 Bs[3][128 * 32];
  const int K = 1024;
  int n0 = blockIdx.x * 128, m0 = blockIdx.y * 64;
  int tid = threadIdx.x;
  int w = tid >> 6, l = tid & 63, cc = l & 15, g = l >> 4;
  int wm = w >> 1, wn = w & 1;
  f32x4 acc[2][4] = {};
  int pxg = ((tid & 3) ^ ((tid >> 3) & 3)) * 8;
  const bf16* Ag = A + (size_t)(m0 + (tid >> 2)) * K + pxg;
  const bf16* Bg = Bt + (size_t)(n0 + (tid >> 2)) * K + pxg;
  int soff = w * 512;
  #define GSTAGE(buf, kt_)                                                      \
    do {                                                                        \
      gload_lds16(Ag + (kt_) * 32, &As[buf][soff]);                             \
      gload_lds16(Bg + (kt_) * 32, &Bs[buf][soff]);                             \
      gload_lds16(Bg + (kt_) * 32 + (size_t)64 * K, &Bs[buf][soff + 2048]);     \
    } while (0)
  GSTAGE(0, 0);
  GSTAGE(1, 1);
  int c0 = 0, c1 = 1, c2 = 2;
  int swz = (g ^ ((cc >> 1) & 3)) * 8;
  for (int kt = 0; kt < 32; ++kt) {
    if (kt + 2 < 32) {
      GSTAGE(c2, kt + 2);
      asm volatile("s_waitcnt vmcnt(6)" ::: "memory");
    } else if (kt + 1 < 32) {
      asm volatile("s_waitcnt vmcnt(3)" ::: "memory");
    } else {
      asm volatile("s_waitcnt vmcnt(0)" ::: "memory");
    }
    __builtin_amdgcn_s_barrier();
    asm volatile("" ::: "memory");
    bf16x8 a[2], bb[4];
    #pragma unroll
    for (int mi = 0; mi < 2; ++mi) a[mi] = *(const bf16x8*)&As[c0][(wm * 32 + mi * 16 + cc) * 32 + swz];
    #pragma unroll
    for (int ni = 0; ni < 4; ++ni) bb[ni] = *(const bf16x8*)&Bs[c0][(wn * 64 + ni * 16 + cc) * 32 + swz];
    #pragma unroll
    for (int mi = 0; mi < 2; ++mi)
      #pragma unroll
      for (int ni = 0; ni < 4; ++ni)
        acc[mi][ni] = __builtin_amdgcn_mfma_f32_16x16x32_bf16(a[mi], bb[ni], acc[mi][ni], 0, 0, 0);
    __builtin_amdgcn_s_barrier();
    asm volatile("" ::: "memory");
    int tmp = c0; c0 = c1; c1 = c2; c2 = tmp;
  }
  #undef GSTAGE
  #pragma unroll
  for (int ni = 0; ni < 4; ++ni) {
    int col = n0 + wn * 64 + ni * 16 + cc;
    float bias = bo[col];
    #pragma unroll
    for (int mi = 0; mi < 2; ++mi)
      #pragma unroll
      for (int r = 0; r < 4; ++r) {
        int row = m0 + wm * 32 + mi * 16 + g * 4 + r;
        out[(size_t)row * 1024 + col] = acc[mi][ni][r] + bias;
      }
  }
}

// ---------------- frame-causal flash attention, swapped-QK^T (lane-local P) ----------------
// r12-proven kernel (f-major block order = balanced per-CU work mix — r14's tile-major
// remap put 4 equal-f siblings on one CU, 8:1 imbalance, +30% — do not regroup).
// Delta vs r12: mask bias folded into the QK^T MFMA C-operand (deletes 16 v_add/chunk).
// No setprio (lockstep waves; m190-class null). 4 blocks/CU.
__global__ __launch_bounds__(256) void k_attn(const bf16* __restrict__ qkv,
                                              const bf16* __restrict__ vt,
                                              const int* __restrict__ mask,
                                              bf16* __restrict__ out) {
  __shared__ __attribute__((aligned(16))) bf16 Ks[2][64 * 64];   // [k][d-slot], slot = chunk ^ pi(k)
  __shared__ __attribute__((aligned(16))) bf16 Vs[2][64 * 64];   // [d][kv-slot], slot = chunk ^ (d&7)
  __shared__ int Ms[2048];
  int wid = blockIdx.x;
  int f = 7 - (wid >> 7);        // heavy frames dispatched first; f-mixed per CU
  int rem = wid & 127;
  int h = rem >> 3;
  int b = (rem >> 2) & 1;
  int tile = rem & 3;
  int t0 = f * 256 + tile * 64;
  int nchunk = (f + 1) * 4;
  int tid = threadIdx.x;
  int w = tid >> 6, l = tid & 63, cc = l & 15, g = l >> 4;

  // staging: dest elem = w*1024 + l*8 (+j*512) -> row = w*16 + j*8 + (l>>3), slot = l&7
  int rbase = w * 16 + (l >> 3);
  int pxk = (l & 7) ^ ((l >> 3) & 3);  // K source chunk (j adds ^4): slot ^ pi(row)
  int pxv = (l & 7) ^ (l >> 3);        // V source chunk (original)
  int ldst = w * 1024 + l * 8;

  int trow = t0 + w * 16 + cc;
  const bf16* qp = qkv + (size_t)((size_t)b * T_ + trow) * 3072 + h * 64;
  bf16x8 aq0 = *(const bf16x8*)(qp + g * 8);
  bf16x8 aq1 = *(const bf16x8*)(qp + 32 + g * 8);
  f32x4 o[4] = {};
  f32x4 o1 = {0.f, 0.f, 0.f, 0.f};
  float m_p = -1e30f;                  // running max for q = cc (lane-local P rows)
  const int* mp = mask + b * T_;

  bf16x8 onesv;
  #pragma unroll
  for (int u = 0; u < 8; ++u) onesv[u] = (bf16)1.0f;

  // stage mask row once (8KB)
  #pragma unroll
  for (int j = 0; j < 2; ++j)
    gload_lds16(mp + w * 512 + j * 256 + l * 4, &Ms[w * 512 + j * 256 + l * 4]);

  #define STAGE(buf, s0_)                                                              \
    do {                                                                               \
      _Pragma("unroll")                                                                \
      for (int j = 0; j < 2; ++j) {                                                    \
        int r_ = rbase + j * 8;                                                        \
        gload_lds16(qkv + (size_t)((size_t)b * T_ + (s0_) + r_) * 3072 + 1024 + h * 64 + ((pxk ^ (j << 2)) << 3), \
                    &Ks[buf][ldst + j * 512]);                                         \
        gload_lds16(vt + (size_t)((size_t)(b * H_ + h) * 64 + r_) * T_ + (s0_) + (pxv << 3), \
                    &Vs[buf][ldst + j * 512]);                                         \
      }                                                                                \
    } while (0)

  STAGE(0, 0);
  // V read swizzle (rows = d, original): slot = chunk ^ (d&7), d&7 = cc&7
  int sw1 = (g ^ (cc & 7)) * 8;
  int sw2 = ((g + 4) ^ (cc & 7)) * 8;
  // K read swizzle (permuted rows rk): slot = chunk ^ pi(rk), pi(rk) = (cc&3)|(((cc>>2)&1)<<2)
  int pik = (cc & 3) | (((cc >> 2) & 1) << 2);
  int swk1 = (g ^ pik) * 8;
  int swk2 = ((g + 4) ^ pik) * 8;
  int rkbase = ((cc >> 2) << 3) | (cc & 3);   // sigma row base

  for (int scn = 0; scn < nchunk; ++scn) {
    int s0 = scn * 64;
    int cur = scn & 1;
    if (scn + 1 < nchunk) {
      STAGE(cur ^ 1, s0 + 64);
      asm volatile("s_waitcnt vmcnt(4)" ::: "memory");
    } else {
      asm volatile("s_waitcnt vmcnt(0)" ::: "memory");
    }
    __builtin_amdgcn_s_barrier();
    asm volatile("" ::: "memory");

    // swapped QK^T with mask bias as the MFMA C-operand:
    // sac[ni][r] = bias + S[q=cc][kv = s0 + 8g + r + 4*(ni&1) + 32*(ni>>1)]
    f32x4 sac[4];
    #pragma unroll
    for (int ni = 0; ni < 4; ++ni) {
      const int4 mi = *(const int4*)&Ms[s0 + ((ni >> 1) << 5) + (g << 3) + ((ni & 1) << 2)];
      f32x4 z;
      z[0] = mi.x ? 0.f : -1e30f;
      z[1] = mi.y ? 0.f : -1e30f;
      z[2] = mi.z ? 0.f : -1e30f;
      z[3] = mi.w ? 0.f : -1e30f;
      int rk = rkbase + ((ni & 1) << 2) + ((ni >> 1) << 5);
      bf16x8 k0 = *(const bf16x8*)&Ks[cur][rk * 64 + swk1];
      bf16x8 k1 = *(const bf16x8*)&Ks[cur][rk * 64 + swk2];
      sac[ni] = __builtin_amdgcn_mfma_f32_16x16x32_bf16(k0, aq0, z, 0, 0, 0);
      sac[ni] = __builtin_amdgcn_mfma_f32_16x16x32_bf16(k1, aq1, sac[ni], 0, 0, 0);
    }

    // defer-max: lane-local 16-value max (all share q = cc)
    float pmax = sac[0][0];
    #pragma unroll
    for (int ni = 0; ni < 4; ++ni)
      #pragma unroll
      for (int r = 0; r < 4; ++r) pmax = fmaxf(pmax, sac[ni][r]);
    if (__any(pmax - m_p > 8.0f)) {
      float mx = pmax;
      mx = fmaxf(mx, __shfl_xor(mx, 16));
      mx = fmaxf(mx, __shfl_xor(mx, 32));
      float mn = fmaxf(m_p, mx);
      float alpha_p = exp2f(m_p - mn);
      m_p = mn;
      #pragma unroll
      for (int r = 0; r < 4; ++r) {
        float ao = __shfl(alpha_p, 4 * g + r);   // alpha for output row q = 4g+r
        #pragma unroll
        for (int ni = 0; ni < 4; ++ni) o[ni][r] *= ao;
        o1[r] *= ao;
      }
    }
    // P = exp2(S - m), pack into PV A-fragments (kv natural order: ap0 elem j = P[cc][8g+j])
    #pragma unroll
    for (int ni = 0; ni < 4; ++ni)
      #pragma unroll
      for (int r = 0; r < 4; ++r)
        sac[ni][r] = exp2f(sac[ni][r] - m_p);
    bf16x8 ap0, ap1;
    #pragma unroll
    for (int j = 0; j < 4; ++j) {
      ap0[j] = (bf16)sac[0][j]; ap0[4 + j] = (bf16)sac[1][j];
      ap1[j] = (bf16)sac[2][j]; ap1[4 + j] = (bf16)sac[3][j];
    }

    // PV + denominator via ones-MFMA (output rows q = 4g+r, cols d = ni*16+cc)
    #pragma unroll
    for (int ni = 0; ni < 4; ++ni) {
      int d = ni * 16 + cc;
      bf16x8 v0 = *(const bf16x8*)&Vs[cur][d * 64 + sw1];
      bf16x8 v1 = *(const bf16x8*)&Vs[cur][d * 64 + sw2];
      o[ni] = __builtin_amdgcn_mfma_f32_16x16x32_bf16(ap0, v0, o[ni], 0, 0, 0);
      o[ni] = __builtin_amdgcn_mfma_f32_16x16x32_bf16(ap1, v1, o[ni], 0, 0, 0);
    }
    o1 = __builtin_amdgcn_mfma_f32_16x16x32_bf16(ap0, onesv, o1, 0, 0, 0);
    o1 = __builtin_amdgcn_mfma_f32_16x16x32_bf16(ap1, onesv, o1, 0, 0, 0);

    __builtin_amdgcn_s_barrier();
    asm volatile("" ::: "memory");
  }
  float rl[4];
  #pragma unroll
  for (int r = 0; r < 4; ++r) rl[r] = 1.0f / o1[r];
  #pragma unroll
  for (int ni = 0; ni < 4; ++ni)
    #pragma unroll
    for (int r = 0; r < 4; ++r) {
      int t = t0 + w * 16 + g * 4 + r;
      out[(size_t)((size_t)b * T_ + t) * 1024 + h * 64 + ni * 16 + cc] = (bf16)(o[ni][r] * rl[r]);
    }
  #undef STAGE
}

extern "C" void kernel_launch(void* const* d_in, const int* in_sizes, int n_in,
                              void* d_out, int out_size, void* d_ws, size_t ws_size,
                              hipStream_t stream) {
  const float* s_frames = (const float*)d_in[0];
  const int* frame_idx  = (const int*)d_in[1];
  const int* seq_idx    = (const int*)d_in[2];
  const int* mask       = (const int*)d_in[3];
  const float* cond     = (const float*)d_in[4];
  const float* W_ada    = (const float*)d_in[5];
  const float* b_ada    = (const float*)d_in[6];
  const float* Wq       = (const float*)d_in[7];
  const float* bq       = (const float*)d_in[8];
  const float* Wk       = (const float*)d_in[9];
  const float* bk       = (const float*)d_in[10];
  const float* Wv       = (const float*)d_in[11];
  const float* bv       = (const float*)d_in[12];
  const float* Wo       = (const float*)d_in[13];
  const float* bo       = (const float*)d_in[14];
  float* out = (float*)d_out;

  char* ws = (char*)d_ws;
  float* ss = (float*)(ws);                                   // 16 KB
  bf16* xb  = (bf16*)(ws + 16384);                            // 8 MB
  bf16* Wt  = (bf16*)(ws + 16384 + 8388608);                  // 8 MB (4096x1024)
  bf16* qkv = (bf16*)(ws + 16384 + 2 * 8388608);              // 24 MB (4096x3072)
  bf16* vt  = (bf16*)(ws + 16384 + 2 * 8388608 + 25165824);   // 8 MB
  bf16* att = (bf16*)(ws + 16384 + 3 * 8388608 + 25165824);   // 8 MB

  k_ada<<<16, 256, 0, stream>>>(cond, W_ada, b_ada, ss);
  k_wt<<<dim3(16, 16, 4), 256, 0, stream>>>(Wq, Wk, Wv, Wo, Wt);
  k_ln<<<4096, 256, 0, stream>>>(s_frames, ss, xb);
  k_gemm_qkv<<<dim3(24, 64), 256, 0, stream>>>(xb, Wt, bq, bk, bv, seq_idx, frame_idx, qkv, vt);
  k_attn<<<1024, 256, 0, stream>>>(qkv, vt, mask, att);
  k_gemm_o<<<dim3(8, 64), 256, 0, stream>>>(att, Wt + (size_t)3072 * 1024, bo, out);
}